// Round 9
// baseline (1753.043 us; speedup 1.0000x reference)
//
#include <hip/hip_runtime.h>

#define R_STAGES 8
#define H_HEADS  8
#define K_CODES  4096
#define C_DIM    128
#define N_TOK    4096      // B*S
#define FEAT     1024      // H*C
#define HKC      (H_HEADS * K_CODES * C_DIM)   // elems per stage

#define MARGIN   1.2e-2f
#define WCAP     512
#define TMS      260       // tmin row stride in fp16 elems
#define TPB      32        // tokens per block

typedef _Float16 half8  __attribute__((ext_vector_type(8)));
typedef _Float16 half4v __attribute__((ext_vector_type(4)));
typedef _Float16 half2v __attribute__((ext_vector_type(2)));
typedef float    f32x4  __attribute__((ext_vector_type(4)));
typedef float    f32x2  __attribute__((ext_vector_type(2)));

#define MFMA16(A, B, C) __builtin_amdgcn_mfma_f32_16x16x32_f16((A), (B), (C), 0, 0, 0)

union H2U { half2v h; int i; };
__device__ __forceinline__ half2v hmin2(half2v a, half2v b) {
    half2v r;
    r[0] = a[0] < b[0] ? a[0] : b[0];
    r[1] = a[1] < b[1] ? a[1] : b[1];
    return r;                                   // v_pk_min_f16
}
__device__ __forceinline__ half2v shfl_xor_h2(half2v v, int m) {
    H2U u; u.h = v; u.i = __shfl_xor(u.i, m); return u.h;
}

// ---------------------------------------------------------------------------
// ws layout (bytes):
//   t    : float    [H][N][C]   @ 0            (16,777,216)
//   ps   : float    [N]         @ 16,777,216   (16,384)
//   cn   : float    [R][H][K]   @ 16,793,600   (1,048,576)
//   cb16 : _Float16             @ 17,842,176   (67,108,864 full / 8,388,608 per-stage)
//   full path needs 84,951,040 B total.
// ---------------------------------------------------------------------------

__global__ void kc_prep(const float* __restrict__ x, float* __restrict__ t,
                        float* __restrict__ ps) {
    int n = blockIdx.x;
    const float* xr = x + (size_t)n * FEAT;

    double ss = 0.0;
    for (int i = threadIdx.x; i < FEAT; i += 256) {
        float v = xr[i];
        ss += (double)v * (double)v;
    }
    for (int off = 32; off > 0; off >>= 1) ss += __shfl_down(ss, off);

    __shared__ double sred[4];
    __shared__ float s_p;
    int wid = threadIdx.x >> 6, lane = threadIdx.x & 63;
    if (lane == 0) sred[wid] = ss;
    __syncthreads();
    if (threadIdx.x == 0) {
        double tot = sred[0] + sred[1] + sred[2] + sred[3];
        float p = (float)sqrt(tot);
        ps[n] = p;
        s_p = p;
    }
    __syncthreads();
    float p = s_p;

    for (int i = threadIdx.x; i < FEAT; i += 256) {
        int c = i & 127;
        float v = xr[(i & ~127) + ((c & 1) << 6) + (c >> 1)];
        size_t o = ((size_t)(i >> 7) * N_TOK + n) * C_DIM + c;
        t[o] = v / p;
    }
}

// Fused fp32->fp16 convert + squared-norm (one pass over cb). One wave/row.
__global__ void kc_cvtn(const float* __restrict__ cb, _Float16* __restrict__ cb16,
                        float* __restrict__ cn) {
    int w = (blockIdx.x << 2) + (threadIdx.x >> 6);
    int lane = threadIdx.x & 63;
    const float* row = cb + (size_t)w * C_DIM;
    float a = row[lane], b = row[lane + 64];
    _Float16* dr = cb16 + (size_t)w * C_DIM;
    dr[lane]      = (_Float16)a;
    dr[lane + 64] = (_Float16)b;
    double s = (double)a * a + (double)b * b;
    for (int off = 32; off > 0; off >>= 1) s += __shfl_down(s, off);
    if (lane == 0) cn[w] = (float)s;
}

// ---------------------------------------------------------------------------
// One residual stage for one (head, 32-token) block. 256 threads = 4 waves,
// each wave scans K/4 = 1024 codes (64 tiles of 16) for all 32 tokens.
// Single fp16-MFMA scan; per-(token,tile) mins to LDS; flagged tiles get
// exact fp64 rescoring; then t -= cb[winner].
// VGPR budget (no spill at the 128 cap from (256,2)):
//   tf 32 + X/Y ring 32 + acc 8 + cv 8 + addressing ~25 ~= 105.
// ---------------------------------------------------------------------------
__device__ __forceinline__ void stage_body(
    const float* __restrict__ cbh32, const _Float16* __restrict__ cbh16,
    const float* __restrict__ cnh, float* __restrict__ th) {

    __shared__ _Float16 tmin[TPB * TMS];    // [tok][tile(256)] fp16 tile-mins
    __shared__ f32x2    rbs[256];           // per-thread running mins (2 groups)
    __shared__ float    mtok[TPB];
    __shared__ int      wl[WCAP];
    __shared__ double   eD[WCAP];
    __shared__ int      eI[WCAP];
    __shared__ int      winner[TPB];
    __shared__ int      wlCnt;

    const int tid  = threadIdx.x;
    const int w    = tid >> 6;              // wave 0..3
    const int lane = tid & 63;
    const int col  = lane & 15;
    const int rblk = lane >> 4;

    if (tid == 0) wlCnt = 0;

    // loop-invariant token fragments: tf[g][j] = t[tok=g*16+col][k=rblk*8+j*32 ..+8]
    half8 tf[2][4];
#pragma unroll
    for (int g = 0; g < 2; ++g) {
        const float* trow = th + (size_t)(g * 16 + col) * C_DIM;
#pragma unroll
        for (int j = 0; j < 4; ++j) {
            const float* p = trow + j * 32 + rblk * 8;
            f32x4 lo = *(const f32x4*)p;
            f32x4 hi = *(const f32x4*)(p + 4);
            half8 v;
            v[0] = (_Float16)lo[0]; v[1] = (_Float16)lo[1];
            v[2] = (_Float16)lo[2]; v[3] = (_Float16)lo[3];
            v[4] = (_Float16)hi[0]; v[5] = (_Float16)hi[1];
            v[6] = (_Float16)hi[2]; v[7] = (_Float16)hi[3];
            tf[g][j] = v;
        }
    }

    const int kbase = w << 10;              // wave's K-quarter (1024 codes, 64 tiles)
    const _Float16* cbA = cbh16 + (size_t)(kbase + col) * C_DIM + rblk * 8;
    const float*    cnA = cnh + kbase + (rblk << 2);

    auto loadA = [&](int it, half8* A, f32x4& cv) {
        const _Float16* p = cbA + (size_t)it * (16 * C_DIM);
#pragma unroll
        for (int j = 0; j < 4; ++j) A[j] = *(const half8*)(p + j * 32);
        cv = *(const f32x4*)(cnA + it * 16);
    };

    half2v rb;
    rb[0] = rb[1] = (_Float16)60000.0f;

    auto screen = [&](const half8* A, const f32x4& cv, int wtile) {
        f32x4 a0 = {0.f,0.f,0.f,0.f}, a1 = {0.f,0.f,0.f,0.f};
#pragma unroll
        for (int j = 0; j < 4; ++j) {
            a0 = MFMA16(A[j], tf[0][j], a0);
            a1 = MFMA16(A[j], tf[1][j], a1);
        }
        float m0 = fminf(fminf(cv[0] - 2.f*a0[0], cv[1] - 2.f*a0[1]),
                         fminf(cv[2] - 2.f*a0[2], cv[3] - 2.f*a0[3]));
        float m1 = fminf(fminf(cv[0] - 2.f*a1[0], cv[1] - 2.f*a1[1]),
                         fminf(cv[2] - 2.f*a1[2], cv[3] - 2.f*a1[3]));
        half2v p;
        p[0] = (_Float16)m0; p[1] = (_Float16)m1;
        // tile min across the 4 rblk lane-groups: 2 packed shuffles
        p = hmin2(p, shfl_xor_h2(p, 16));
        p = hmin2(p, shfl_xor_h2(p, 32));
        rb = hmin2(rb, p);
        if (rblk == 0) {
            tmin[(col)      * TMS + wtile] = p[0];
            tmin[(16 + col) * TMS + wtile] = p[1];
        }
    };

    // ---- single scan, register double-buffer (depth 2) ----
    {
        half8 X[4], Y[4];
        f32x4 vx, vy;
        loadA(0, X, vx); loadA(1, Y, vy);
        const int wbase = w << 6;
#pragma unroll 1
        for (int j = 0; j < 32; ++j) {
            const int b2 = j << 1;
            screen(X, vx, wbase + b2);
            if (j < 31) loadA(b2 + 2, X, vx);
            screen(Y, vy, wbase + b2 + 1);
            if (j < 31) loadA(b2 + 3, Y, vy);
        }
    }
    {
        f32x2 s; s[0] = (float)rb[0]; s[1] = (float)rb[1];
        rbs[tid] = s;
    }
    __syncthreads();

    // ---- per-token screened min ----
    if (tid < TPB) {
        const int g = tid >> 4, c2 = tid & 15;
        float m = 3.4e38f;
#pragma unroll
        for (int ww = 0; ww < 4; ++ww) m = fminf(m, rbs[(ww << 6) + c2][g]);
        mtok[tid] = m;
    }
    __syncthreads();

    // ---- build worklist of flagged (token, tile) pairs ----
    {
        const int tok = tid >> 3, q = tid & 7;   // 8 threads/token, 32 tiles each
        const float thr = mtok[tok] + MARGIN;
        const half4v* rowp = (const half4v*)(tmin + tok * TMS + (q << 5));
#pragma unroll 2
        for (int j4 = 0; j4 < 8; ++j4) {
            half4v v = rowp[j4];
#pragma unroll
            for (int e = 0; e < 4; ++e) {
                if ((float)v[e] < thr) {
                    int idx = atomicAdd(&wlCnt, 1);
                    if (idx < WCAP) wl[idx] = (tok << 8) | ((q << 5) + (j4 << 2) + e);
                }
            }
        }
    }
    __syncthreads();

    int E = wlCnt;
    if (E <= WCAP) {
        // ---- fp64 rescore: one 16-lane group per flagged tile (16/batch) ----
        for (int e0 = 0; e0 < E; e0 += 16) {
            const int e = e0 + (tid >> 4);
            double bd = 1e300; int bi = 0x7fffffff;
            if (e < E) {
                const int meta = wl[e];
                const int tok = meta >> 8;
                const int k = ((meta & 255) << 4) + (tid & 15);
                const float* crow = cbh32 + (size_t)k * C_DIM;
                const float* trw  = th + (size_t)tok * C_DIM;
                double cx0=0,cx1=0,cx2=0,cx3=0,d0=0,d1=0,d2=0,d3=0;
#pragma unroll 4
                for (int c = 0; c < C_DIM; c += 4) {
                    double cv0 = crow[c],   tv0 = trw[c];
                    double cv1 = crow[c+1], tv1 = trw[c+1];
                    double cv2 = crow[c+2], tv2 = trw[c+2];
                    double cv3 = crow[c+3], tv3 = trw[c+3];
                    cx0 = fma(cv0,cv0,cx0); d0 = fma(tv0,cv0,d0);
                    cx1 = fma(cv1,cv1,cx1); d1 = fma(tv1,cv1,d1);
                    cx2 = fma(cv2,cv2,cx2); d2 = fma(tv2,cv2,d2);
                    cx3 = fma(cv3,cv3,cx3); d3 = fma(tv3,cv3,d3);
                }
                bd = ((cx0+cx1)+(cx2+cx3)) - 2.0*((d0+d1)+(d2+d3));
                bi = k;
            }
#pragma unroll
            for (int off = 1; off < 16; off <<= 1) {
                double od = __shfl_xor(bd, off);
                int    oi = __shfl_xor(bi, off);
                if (od < bd || (od == bd && oi < bi)) { bd = od; bi = oi; }
            }
            if ((tid & 15) == 0 && e < E) { eD[e] = bd; eI[e] = bi; }
        }
        __syncthreads();
        if (tid < TPB) {
            double bd = 1e300; int bi = 0x7fffffff;
            for (int e = 0; e < E; ++e) {
                if ((wl[e] >> 8) == tid) {
                    double d = eD[e]; int i2 = eI[e];
                    if (d < bd || (d == bd && i2 < bi)) { bd = d; bi = i2; }
                }
            }
            winner[tid] = bi;
        }
        __syncthreads();
    } else {
        // ---- overflow fallback (prob ~0): full fp64 scan, all tokens ----
        for (int ot = 0; ot < TPB; ++ot) {
            const float* trw = th + (size_t)ot * C_DIM;
            double bd = 1e300; int bi = 0x7fffffff;
            for (int k = tid; k < K_CODES; k += 256) {
                const float* crow = cbh32 + (size_t)k * C_DIM;
                double cx0=0,cx1=0,cx2=0,cx3=0,d0=0,d1=0,d2=0,d3=0;
                for (int c = 0; c < C_DIM; c += 4) {
                    double cv0 = crow[c],   tv0 = trw[c];
                    double cv1 = crow[c+1], tv1 = trw[c+1];
                    double cv2 = crow[c+2], tv2 = trw[c+2];
                    double cv3 = crow[c+3], tv3 = trw[c+3];
                    cx0 = fma(cv0,cv0,cx0); d0 = fma(tv0,cv0,d0);
                    cx1 = fma(cv1,cv1,cx1); d1 = fma(tv1,cv1,d1);
                    cx2 = fma(cv2,cv2,cx2); d2 = fma(tv2,cv2,d2);
                    cx3 = fma(cv3,cv3,cx3); d3 = fma(tv3,cv3,d3);
                }
                double d = ((cx0+cx1)+(cx2+cx3)) - 2.0*((d0+d1)+(d2+d3));
                if (d < bd || (d == bd && k < bi)) { bd = d; bi = k; }
            }
            for (int off = 1; off <= 32; off <<= 1) {
                double od = __shfl_xor(bd, off);
                int    oi = __shfl_xor(bi, off);
                if (od < bd || (od == bd && oi < bi)) { bd = od; bi = oi; }
            }
            if (lane == 0) { eD[w] = bd; eI[w] = bi; }
            __syncthreads();
            if (tid == 0) {
                double b2 = eD[0]; int i2 = eI[0];
                for (int q = 1; q < 4; ++q) {
                    if (eD[q] < b2 || (eD[q] == b2 && eI[q] < i2)) { b2 = eD[q]; i2 = eI[q]; }
                }
                winner[ot] = i2;
            }
            __syncthreads();
        }
    }

    // ---- residual update: t -= cb[winner] (fp32, matches reference) ----
    for (int i = tid; i < TPB * C_DIM; i += 256) {
        const int tok = i >> 7, c = i & 127;
        th[(size_t)tok * C_DIM + c] -= cbh32[(size_t)winner[tok] * C_DIM + c];
    }
    __syncthreads();
}

// All 8 stages in one kernel — residual chain is per-token independent.
__global__ __launch_bounds__(256, 2)
void kc_all(const float* __restrict__ cb32, const _Float16* __restrict__ cb16,
            const float* __restrict__ cn, float* __restrict__ t) {
    const int h  = blockIdx.x & 7;               // XCD-affine head mapping
    const int n0 = (blockIdx.x >> 3) * TPB;
    float* th = t + ((size_t)h * N_TOK + n0) * C_DIM;
#pragma unroll 1
    for (int r = 0; r < R_STAGES; ++r) {
        const size_t off = (size_t)(r * H_HEADS + h) * K_CODES;
        stage_body(cb32 + off * C_DIM, cb16 + off * C_DIM, cn + off, th);
    }
}

// Single-stage variant (used when ws can't hold the full fp16 codebook).
__global__ __launch_bounds__(256, 2)
void kc_stage_one(const float* __restrict__ cb32, const _Float16* __restrict__ cb16,
                  const float* __restrict__ cn, float* __restrict__ t) {
    const int h  = blockIdx.x & 7;
    const int n0 = (blockIdx.x >> 3) * TPB;
    float* th = t + ((size_t)h * N_TOK + n0) * C_DIM;
    const size_t off = (size_t)h * K_CODES;
    stage_body(cb32 + off * C_DIM, cb16 + off * C_DIM, cn + off, th);
}

__global__ void kc_out(const float* __restrict__ x, const float* __restrict__ t,
                       const float* __restrict__ ps, float* __restrict__ out) {
    int n = blockIdx.x;
    float p = ps[n];
    const float* xr = x + (size_t)n * FEAT;
    for (int i = threadIdx.x; i < FEAT; i += 256) {
        int c = i & 127;
        float v = xr[(i & ~127) + ((c & 1) << 6) + (c >> 1)];
        float t0 = v / p;
        float tf = t[((size_t)(i >> 7) * N_TOK + n) * C_DIM + c];
        out[(size_t)n * FEAT + i] = (t0 - tf) * p;
    }
}

extern "C" void kernel_launch(void* const* d_in, const int* in_sizes, int n_in,
                              void* d_out, int out_size, void* d_ws, size_t ws_size,
                              hipStream_t stream) {
    const float* x  = (const float*)d_in[0];
    const float* cb = (const float*)d_in[1];
    float* out = (float*)d_out;

    float*    t    = (float*)d_ws;
    float*    ps   = (float*)((char*)d_ws + 16777216);
    float*    cn   = (float*)((char*)d_ws + 16793600);
    _Float16* cb16 = (_Float16*)((char*)d_ws + 17842176);

    const bool full = (ws_size >= 84951040ull);   // 17,842,176 + 67,108,864

    kc_prep<<<N_TOK, 256, 0, stream>>>(x, t, ps);

    if (full) {
        kc_cvtn<<<(R_STAGES * H_HEADS * K_CODES) / 4, 256, 0, stream>>>(cb, cb16, cn);
        kc_all<<<H_HEADS * (N_TOK / TPB), 256, 0, stream>>>(cb, cb16, cn, t);
    } else {
        for (int r = 0; r < R_STAGES; ++r) {
            kc_cvtn<<<(H_HEADS * K_CODES) / 4, 256, 0, stream>>>(
                cb + (size_t)r * HKC, cb16, cn + (size_t)r * H_HEADS * K_CODES);
            kc_stage_one<<<H_HEADS * (N_TOK / TPB), 256, 0, stream>>>(
                cb + (size_t)r * HKC, cb16, cn + (size_t)r * H_HEADS * K_CODES, t);
        }
    }

    kc_out<<<N_TOK, 256, 0, stream>>>(x, t, ps, out);
}

// Round 10
// 1147.886 us; speedup vs baseline: 1.5272x; 1.5272x over previous
//
#include <hip/hip_runtime.h>

#define R_STAGES 8
#define H_HEADS  8
#define K_CODES  4096
#define C_DIM    128
#define N_TOK    4096      // B*S
#define FEAT     1024      // H*C
#define HKC      (H_HEADS * K_CODES * C_DIM)   // elems per stage

#define MARGIN   1.2e-2f
#define WCAP     384
#define TMS      260       // tmin row stride in fp16 elems (256 tiles + pad)
#define NTILE    64        // codes staged per phase
#define NPH      (K_CODES / NTILE)             // 64 phases
#define TPB      64        // tokens per block (4 waves x 16)

typedef _Float16 half8  __attribute__((ext_vector_type(8)));
typedef _Float16 half4v __attribute__((ext_vector_type(4)));
typedef float    f32x4  __attribute__((ext_vector_type(4)));

#define MFMA16(A, B, C) __builtin_amdgcn_mfma_f32_16x16x32_f16((A), (B), (C), 0, 0, 0)

__device__ __forceinline__ void glds16(const _Float16* g, _Float16* l) {
    __builtin_amdgcn_global_load_lds(
        (const __attribute__((address_space(1))) void*)g,
        (__attribute__((address_space(3))) void*)l, 16, 0, 0);
}

// ---------------------------------------------------------------------------
// ws layout (bytes):
//   t    : float    [H][N][C]   @ 0            (16,777,216)
//   ps   : float    [N]         @ 16,777,216   (16,384)
//   cn   : float    [R][H][K]   @ 16,793,600   (1,048,576)
//   cb16 : _Float16             @ 17,842,176   (67,108,864 full / 8,388,608 per-stage)
//   full path needs 84,951,040 B total.
// ---------------------------------------------------------------------------

__global__ void kc_prep(const float* __restrict__ x, float* __restrict__ t,
                        float* __restrict__ ps) {
    int n = blockIdx.x;
    const float* xr = x + (size_t)n * FEAT;

    double ss = 0.0;
    for (int i = threadIdx.x; i < FEAT; i += 256) {
        float v = xr[i];
        ss += (double)v * (double)v;
    }
    for (int off = 32; off > 0; off >>= 1) ss += __shfl_down(ss, off);

    __shared__ double sred[4];
    __shared__ float s_p;
    int wid = threadIdx.x >> 6, lane = threadIdx.x & 63;
    if (lane == 0) sred[wid] = ss;
    __syncthreads();
    if (threadIdx.x == 0) {
        double tot = sred[0] + sred[1] + sred[2] + sred[3];
        float p = (float)sqrt(tot);
        ps[n] = p;
        s_p = p;
    }
    __syncthreads();
    float p = s_p;

    for (int i = threadIdx.x; i < FEAT; i += 256) {
        int c = i & 127;
        float v = xr[(i & ~127) + ((c & 1) << 6) + (c >> 1)];
        size_t o = ((size_t)(i >> 7) * N_TOK + n) * C_DIM + c;
        t[o] = v / p;
    }
}

// Fused fp32->fp16 convert + squared-norm (one pass over cb). One wave/row.
__global__ void kc_cvtn(const float* __restrict__ cb, _Float16* __restrict__ cb16,
                        float* __restrict__ cn) {
    int w = (blockIdx.x << 2) + (threadIdx.x >> 6);
    int lane = threadIdx.x & 63;
    const float* row = cb + (size_t)w * C_DIM;
    float a = row[lane], b = row[lane + 64];
    _Float16* dr = cb16 + (size_t)w * C_DIM;
    dr[lane]      = (_Float16)a;
    dr[lane + 64] = (_Float16)b;
    double s = (double)a * a + (double)b * b;
    for (int off = 32; off > 0; off >>= 1) s += __shfl_down(s, off);
    if (lane == 0) cn[w] = (float)s;
}

// ---------------------------------------------------------------------------
// One residual stage, one (head, 64-token) block. 256 threads = 4 waves; waves
// own disjoint 16-token groups. All waves share a double-buffered 64-code LDS
// tile (16 KB) staged block-cooperatively via global_load_lds (pre-swizzled
// source so swizzled ds_read_b128 is low-conflict); classic 2-phase loop with
// __syncthreads (m97 structure). Single fp16-MFMA scan records per-(token,
// 16-code-tile) mins; flagged tiles get exact fp64 rescoring; t -= cb[winner].
// ---------------------------------------------------------------------------
__device__ __forceinline__ void stage_body(
    const float* __restrict__ cbh32, const _Float16* __restrict__ cbh16,
    const float* __restrict__ cnh, float* __restrict__ th) {

    __shared__ __align__(16) _Float16 buf[2][NTILE * C_DIM];  // 32,768 B
    __shared__ __align__(16) _Float16 tmin[TPB * TMS];        // 33,280 B
    __shared__ float    mtok[TPB];
    __shared__ int      wl[WCAP];
    __shared__ double   eD[WCAP];
    __shared__ int      eI[WCAP];
    __shared__ int      winner[TPB];
    __shared__ int      wlCnt;

    const int tid  = threadIdx.x;
    const int w    = tid >> 6;              // wave 0..3 (token group)
    const int lane = tid & 63;
    const int col  = lane & 15;
    const int rblk = lane >> 4;
    const int tok  = (w << 4) + col;        // this lane's token

    if (tid == 0) wlCnt = 0;

    // loop-invariant token fragment: tf[j] = t[tok][k = rblk*8 + j*32 .. +8]
    half8 tf[4];
    {
        const float* trow = th + (size_t)tok * C_DIM;
#pragma unroll
        for (int j = 0; j < 4; ++j) {
            const float* p = trow + j * 32 + rblk * 8;
            f32x4 lo = *(const f32x4*)p;
            f32x4 hi = *(const f32x4*)(p + 4);
            half8 v;
            v[0] = (_Float16)lo[0]; v[1] = (_Float16)lo[1];
            v[2] = (_Float16)lo[2]; v[3] = (_Float16)lo[3];
            v[4] = (_Float16)hi[0]; v[5] = (_Float16)hi[1];
            v[6] = (_Float16)hi[2]; v[7] = (_Float16)hi[3];
            tf[j] = v;
        }
    }

    // stage phase-p 64-code tile (16 KB) into buf[bsel], block-cooperatively.
    // Per wave: 4 glds16 of 1 KB each. Source pre-swizzled with the involution
    // a ^= ((a>>8 & 15) << 4) so swizzled ds_reads are low-conflict (G21).
    auto stageT = [&](int p, int bsel) {
        const char* gt = (const char*)cbh16 + (size_t)p * (NTILE * 256);
        _Float16* lb = buf[bsel];
#pragma unroll
        for (int i = 0; i < 4; ++i) {
            const int base = (w << 12) + (i << 10);        // wave-uniform bytes
            const int d    = base + (lane << 4);           // per-lane dest
            const int src  = d ^ (((d >> 8) & 15) << 4);
            glds16((const _Float16*)(gt + src), lb + (base >> 1));
        }
    };

    float rb = 3.4e38f;

    // compute phase p from buf[bsel]: 4 subtiles x (4 ds_read_b128 + 4 MFMA)
    auto computeT = [&](int p, int bsel) {
        const _Float16* bp = buf[bsel];
        const float* cpp = cnh + p * NTILE + (rblk << 2);
        f32x4 cv[4];
        cv[0] = *(const f32x4*)cpp;
        cv[1] = *(const f32x4*)(cpp + 16);
        cv[2] = *(const f32x4*)(cpp + 32);
        cv[3] = *(const f32x4*)(cpp + 48);
#pragma unroll
        for (int sub = 0; sub < 4; ++sub) {
            const int row  = (sub << 4) + col;
            const int base = (row << 8) + (rblk << 4);     // bytes
            const int swz  = (row & 15) << 4;
            f32x4 acc = {0.f, 0.f, 0.f, 0.f};
#pragma unroll
            for (int j = 0; j < 4; ++j) {
                half8 A = *(const half8*)(bp + (((base + (j << 6)) ^ swz) >> 1));
                acc = MFMA16(A, tf[j], acc);
            }
            float m = fminf(fminf(cv[sub][0] - 2.f * acc[0], cv[sub][1] - 2.f * acc[1]),
                            fminf(cv[sub][2] - 2.f * acc[2], cv[sub][3] - 2.f * acc[3]));
            float tm = fminf(m, __shfl_xor(m, 16));
            tm = fminf(tm, __shfl_xor(tm, 32));
            rb = fminf(rb, tm);
            if (rblk == 0) tmin[tok * TMS + (p << 2) + sub] = (_Float16)tm;
        }
    };

    // ---- 2-phase scan (m97 structure): stage(p+1) || compute(p), sync ----
    stageT(0, 0);
    __syncthreads();
#pragma unroll 1
    for (int p = 0; p < NPH; ++p) {
        if (p + 1 < NPH) stageT(p + 1, (p + 1) & 1);
        computeT(p, p & 1);
        __syncthreads();
    }

    // ---- per-token screened min (waves own disjoint tokens) ----
    if (rblk == 0) mtok[tok] = rb;
    __syncthreads();

    // ---- flag (token, 16-code-tile) pairs within MARGIN of token min ----
    {
        const int tk = tid >> 2, q = tid & 3;   // 4 threads/token, 64 tiles each
        const float thr = mtok[tk] + MARGIN;
        const half4v* rowp = (const half4v*)(tmin + tk * TMS + (q << 6));
#pragma unroll 4
        for (int j4 = 0; j4 < 16; ++j4) {
            half4v v = rowp[j4];
#pragma unroll
            for (int e = 0; e < 4; ++e) {
                if ((float)v[e] < thr) {
                    int idx = atomicAdd(&wlCnt, 1);
                    if (idx < WCAP) wl[idx] = (tk << 8) | ((q << 6) + (j4 << 2) + e);
                }
            }
        }
    }
    __syncthreads();

    int E = wlCnt;
    if (E <= WCAP) {
        // ---- fp64 rescore: one 16-lane group per flagged 16-code tile ----
        for (int e0 = 0; e0 < E; e0 += 16) {
            const int e = e0 + (tid >> 4);
            double bd = 1e300; int bi = 0x7fffffff;
            if (e < E) {
                const int meta = wl[e];
                const int tk = meta >> 8;
                const int k = ((meta & 255) << 4) + (tid & 15);
                const float* crow = cbh32 + (size_t)k * C_DIM;
                const float* trw  = th + (size_t)tk * C_DIM;
                double cx0=0,cx1=0,cx2=0,cx3=0,d0=0,d1=0,d2=0,d3=0;
#pragma unroll 4
                for (int c = 0; c < C_DIM; c += 4) {
                    double cv0 = crow[c],   tv0 = trw[c];
                    double cv1 = crow[c+1], tv1 = trw[c+1];
                    double cv2 = crow[c+2], tv2 = trw[c+2];
                    double cv3 = crow[c+3], tv3 = trw[c+3];
                    cx0 = fma(cv0,cv0,cx0); d0 = fma(tv0,cv0,d0);
                    cx1 = fma(cv1,cv1,cx1); d1 = fma(tv1,cv1,d1);
                    cx2 = fma(cv2,cv2,cx2); d2 = fma(tv2,cv2,d2);
                    cx3 = fma(cv3,cv3,cx3); d3 = fma(tv3,cv3,d3);
                }
                bd = ((cx0+cx1)+(cx2+cx3)) - 2.0*((d0+d1)+(d2+d3));
                bi = k;
            }
#pragma unroll
            for (int off = 1; off < 16; off <<= 1) {
                double od = __shfl_xor(bd, off);
                int    oi = __shfl_xor(bi, off);
                if (od < bd || (od == bd && oi < bi)) { bd = od; bi = oi; }
            }
            if ((tid & 15) == 0 && e < E) { eD[e] = bd; eI[e] = bi; }
        }
        __syncthreads();
        if (tid < TPB) {
            double bd = 1e300; int bi = 0x7fffffff;
            for (int e = 0; e < E; ++e) {
                if ((wl[e] >> 8) == tid) {
                    double d = eD[e]; int i2 = eI[e];
                    if (d < bd || (d == bd && i2 < bi)) { bd = d; bi = i2; }
                }
            }
            winner[tid] = bi;
        }
        __syncthreads();
    } else {
        // ---- overflow fallback (prob ~0): full fp64 scan, all tokens ----
        for (int ot = 0; ot < TPB; ++ot) {
            const float* trw = th + (size_t)ot * C_DIM;
            double bd = 1e300; int bi = 0x7fffffff;
            for (int k = tid; k < K_CODES; k += 256) {
                const float* crow = cbh32 + (size_t)k * C_DIM;
                double cx0=0,cx1=0,cx2=0,cx3=0,d0=0,d1=0,d2=0,d3=0;
                for (int c = 0; c < C_DIM; c += 4) {
                    double cv0 = crow[c],   tv0 = trw[c];
                    double cv1 = crow[c+1], tv1 = trw[c+1];
                    double cv2 = crow[c+2], tv2 = trw[c+2];
                    double cv3 = crow[c+3], tv3 = trw[c+3];
                    cx0 = fma(cv0,cv0,cx0); d0 = fma(tv0,cv0,d0);
                    cx1 = fma(cv1,cv1,cx1); d1 = fma(tv1,cv1,d1);
                    cx2 = fma(cv2,cv2,cx2); d2 = fma(tv2,cv2,d2);
                    cx3 = fma(cv3,cv3,cx3); d3 = fma(tv3,cv3,d3);
                }
                double d = ((cx0+cx1)+(cx2+cx3)) - 2.0*((d0+d1)+(d2+d3));
                if (d < bd || (d == bd && k < bi)) { bd = d; bi = k; }
            }
            for (int off = 1; off <= 32; off <<= 1) {
                double od = __shfl_xor(bd, off);
                int    oi = __shfl_xor(bi, off);
                if (od < bd || (od == bd && oi < bi)) { bd = od; bi = oi; }
            }
            if (lane == 0) { eD[w] = bd; eI[w] = bi; }
            __syncthreads();
            if (tid == 0) {
                double b2 = eD[0]; int i2 = eI[0];
                for (int q = 1; q < 4; ++q) {
                    if (eD[q] < b2 || (eD[q] == b2 && eI[q] < i2)) { b2 = eD[q]; i2 = eI[q]; }
                }
                winner[ot] = i2;
            }
            __syncthreads();
        }
    }

    // ---- residual update: t -= cb[winner] (fp32, matches reference) ----
    for (int i = tid; i < TPB * C_DIM; i += 256) {
        const int tk = i >> 7, c = i & 127;
        th[(size_t)tk * C_DIM + c] -= cbh32[(size_t)winner[tk] * C_DIM + c];
    }
    __syncthreads();
}

// All 8 stages in one kernel — residual chain is per-token independent.
__global__ __launch_bounds__(256, 2)
void kc_all(const float* __restrict__ cb32, const _Float16* __restrict__ cb16,
            const float* __restrict__ cn, float* __restrict__ t) {
    const int h  = blockIdx.x & 7;               // XCD-affine head mapping
    const int n0 = (blockIdx.x >> 3) * TPB;
    float* th = t + ((size_t)h * N_TOK + n0) * C_DIM;
#pragma unroll 1
    for (int r = 0; r < R_STAGES; ++r) {
        const size_t off = (size_t)(r * H_HEADS + h) * K_CODES;
        stage_body(cb32 + off * C_DIM, cb16 + off * C_DIM, cn + off, th);
    }
}

// Single-stage variant (used when ws can't hold the full fp16 codebook).
__global__ __launch_bounds__(256, 2)
void kc_stage_one(const float* __restrict__ cb32, const _Float16* __restrict__ cb16,
                  const float* __restrict__ cn, float* __restrict__ t) {
    const int h  = blockIdx.x & 7;
    const int n0 = (blockIdx.x >> 3) * TPB;
    float* th = t + ((size_t)h * N_TOK + n0) * C_DIM;
    const size_t off = (size_t)h * K_CODES;
    stage_body(cb32 + off * C_DIM, cb16 + off * C_DIM, cn + off, th);
}

__global__ void kc_out(const float* __restrict__ x, const float* __restrict__ t,
                       const float* __restrict__ ps, float* __restrict__ out) {
    int n = blockIdx.x;
    float p = ps[n];
    const float* xr = x + (size_t)n * FEAT;
    for (int i = threadIdx.x; i < FEAT; i += 256) {
        int c = i & 127;
        float v = xr[(i & ~127) + ((c & 1) << 6) + (c >> 1)];
        float t0 = v / p;
        float tf = t[((size_t)(i >> 7) * N_TOK + n) * C_DIM + c];
        out[(size_t)n * FEAT + i] = (t0 - tf) * p;
    }
}

extern "C" void kernel_launch(void* const* d_in, const int* in_sizes, int n_in,
                              void* d_out, int out_size, void* d_ws, size_t ws_size,
                              hipStream_t stream) {
    const float* x  = (const float*)d_in[0];
    const float* cb = (const float*)d_in[1];
    float* out = (float*)d_out;

    float*    t    = (float*)d_ws;
    float*    ps   = (float*)((char*)d_ws + 16777216);
    float*    cn   = (float*)((char*)d_ws + 16793600);
    _Float16* cb16 = (_Float16*)((char*)d_ws + 17842176);

    const bool full = (ws_size >= 84951040ull);   // 17,842,176 + 67,108,864

    kc_prep<<<N_TOK, 256, 0, stream>>>(x, t, ps);

    if (full) {
        kc_cvtn<<<(R_STAGES * H_HEADS * K_CODES) / 4, 256, 0, stream>>>(cb, cb16, cn);
        kc_all<<<H_HEADS * (N_TOK / TPB), 256, 0, stream>>>(cb, cb16, cn, t);
    } else {
        for (int r = 0; r < R_STAGES; ++r) {
            kc_cvtn<<<(H_HEADS * K_CODES) / 4, 256, 0, stream>>>(
                cb + (size_t)r * HKC, cb16, cn + (size_t)r * H_HEADS * K_CODES);
            kc_stage_one<<<H_HEADS * (N_TOK / TPB), 256, 0, stream>>>(
                cb + (size_t)r * HKC, cb16, cn + (size_t)r * H_HEADS * K_CODES, t);
        }
    }

    kc_out<<<N_TOK, 256, 0, stream>>>(x, t, ps, out);
}